// Round 7
// baseline (203.238 us; speedup 1.0000x reference)
//
#include <hip/hip_runtime.h>

#define NN 20000
#define NE 320000
#define FD 128
#define KTOT 640   // 4*128 (relations) + 128 (root/self)
#define BM 32      // rows per GEMM block

typedef float f32x4 __attribute__((ext_vector_type(4)));
typedef __bf16 bf16x8 __attribute__((ext_vector_type(8)));

__device__ __forceinline__ unsigned f2ord(float f) {
  unsigned u = __float_as_uint(f);
  return (u & 0x80000000u) ? ~u : (u | 0x80000000u);
}
__device__ __forceinline__ float ord2f(unsigned u) {
  return (u & 0x80000000u) ? __uint_as_float(u & 0x7FFFFFFFu) : __uint_as_float(~u);
}
__device__ __forceinline__ unsigned pkbf(float a, float b) {
  union { __bf16 h[2]; unsigned u; } p;
  p.h[0] = (__bf16)a; p.h[1] = (__bf16)b; return p.u;
}

// one prep kernel: mm seed, deg zero, x->bf16 pack, both layers' wt (B^T) build
__global__ void prep_kernel(unsigned* mm, int* deg,
                            const float* __restrict__ x, unsigned* __restrict__ xb,
                            const float* __restrict__ W1, const float* __restrict__ r1,
                            const float* __restrict__ W2, const float* __restrict__ r2,
                            __bf16* __restrict__ wt1, __bf16* __restrict__ wt2) {
  int i = blockIdx.x * blockDim.x + threadIdx.x;
  if (i == 0) { mm[0] = 0xFFFFFFFFu; mm[1] = 0u; }
  if (i < NN) deg[i] = 0;
  if (i < 2 * FD * KTOT) {
    int which = i / (FD * KTOT);
    int rem = i % (FD * KTOT);
    int n = rem / KTOT, k = rem % KTOT;
    const float* W = which ? W2 : W1;
    const float* rt = which ? r2 : r1;
    float v = (k < 512) ? W[(size_t)k * FD + n] : rt[(size_t)(k - 512) * FD + n];
    (which ? wt2 : wt1)[rem] = (__bf16)v;
  }
  if (i < NN * FD / 4) {
    float4 v = *(const float4*)(x + (size_t)i * 4);
    uint2 p;
    p.x = pkbf(v.x, v.y);
    p.y = pkbf(v.z, v.w);
    *(uint2*)(xb + (size_t)i * 2) = p;
  }
}

__global__ void histmm_kernel(const int* __restrict__ dst, const float* __restrict__ ew,
                              int* deg, unsigned* mm) {
  __shared__ unsigned smn[256], smx[256];
  unsigned lmn = 0xFFFFFFFFu, lmx = 0u;
  for (int i = blockIdx.x * blockDim.x + threadIdx.x; i < NE; i += gridDim.x * blockDim.x) {
    atomicAdd(&deg[dst[i]], 1);
    unsigned o = f2ord(ew[i]);
    lmn = (o < lmn) ? o : lmn;
    lmx = (o > lmx) ? o : lmx;
  }
  smn[threadIdx.x] = lmn; smx[threadIdx.x] = lmx;
  __syncthreads();
  for (int s = 128; s > 0; s >>= 1) {
    if (threadIdx.x < s) {
      unsigned a = smn[threadIdx.x], b = smn[threadIdx.x + s];
      smn[threadIdx.x] = (b < a) ? b : a;
      unsigned c = smx[threadIdx.x], d = smx[threadIdx.x + s];
      smx[threadIdx.x] = (d > c) ? d : c;
    }
    __syncthreads();
  }
  if (threadIdx.x == 0) { atomicMin(&mm[0], smn[0]); atomicMax(&mm[1], smx[0]); }
}

__global__ void scan_kernel(const int* __restrict__ deg, int* offs, int* cursor) {
  __shared__ int part[1024];
  const int CH = (NN + 1023) / 1024;  // 20
  int t = threadIdx.x;
  int b = t * CH;
  int e = (b + CH < NN) ? (b + CH) : NN;
  int s = 0;
  for (int i = b; i < e; ++i) s += deg[i];
  part[t] = s;
  __syncthreads();
  for (int off = 1; off < 1024; off <<= 1) {
    int v = part[t];
    int add = (t >= off) ? part[t - off] : 0;
    __syncthreads();
    part[t] = v + add;
    __syncthreads();
  }
  int excl = (t == 0) ? 0 : part[t - 1];
  for (int i = b; i < e; ++i) { offs[i] = excl; cursor[i] = excl; excl += deg[i]; }
  if (t == 1023) offs[NN] = part[1023];
}

__global__ void fill_kernel(const int* __restrict__ src, const int* __restrict__ dst,
                            const int* __restrict__ et, const float* __restrict__ ew,
                            const unsigned* __restrict__ mm, int* cursor,
                            int2* __restrict__ ed) {
  int e = blockIdx.x * blockDim.x + threadIdx.x;
  if (e >= NE) return;
  float mn = ord2f(mm[0]), mx = ord2f(mm[1]);
  float inv = 1.0f / (mx - mn + 1e-8f);
  int d = dst[e];
  int pos = atomicAdd(&cursor[d], 1);
  ed[pos] = make_int2(src[e] | (et[e] << 28), __float_as_int((ew[e] - mn) * inv));
}

// ---------------------------------------------------------------------------
// Aggregation v6 (macro-hygiene fixed): block = 256 thr = 4 waves = ONE node.
// Wave w handles edge offsets ≡ w (mod 4) with a 4-unrolled body (4
// independent record+gather chains in flight). Combine: waves 1-3 dump
// partials to LDS; wave 0 sums and writes the g row (4 rel slots + self).
// ---------------------------------------------------------------------------
__global__ __launch_bounds__(256) void aggregate_kernel(
    const unsigned* __restrict__ xb,   // [NN][64] packed bf16 pairs
    const int* __restrict__ offs, const int2* __restrict__ ed,
    unsigned* __restrict__ g) {        // [NN][320] u32
  __shared__ float2 part[3][4][64];    // wave-1..3 partials: [w][rel][lane], 6 KB
  int node = blockIdx.x;
  int wave = threadIdx.x >> 6, lane = threadIdx.x & 63;
  int beg = offs[node], end = offs[node + 1];
  float a00 = 0.f, a01 = 0.f, a10 = 0.f, a11 = 0.f;
  float a20 = 0.f, a21 = 0.f, a30 = 0.f, a31 = 0.f;

  // NOTE: all macro-internal names end in '_' — R6 failed because internals
  // named w0..w3 shadowed caller arguments of the same name (the initializer
  // of `float w0 = ...(w0)...` binds to the NEW w0 -> uninitialized).
#define ACCW(E, U, WV)                                                   \
  do {                                                                   \
    float zp0_ = __uint_as_float((U) << 16);                             \
    float zp1_ = __uint_as_float((U) & 0xFFFF0000u);                     \
    unsigned zr_ = ((unsigned)(E).x) >> 28;                              \
    float zw0_ = (zr_ == 0) ? (WV) : 0.f;                                \
    float zw1_ = (zr_ == 1) ? (WV) : 0.f;                                \
    float zw2_ = (zr_ == 2) ? (WV) : 0.f;                                \
    float zw3_ = (zr_ == 3) ? (WV) : 0.f;                                \
    a00 += zw0_ * zp0_; a01 += zw0_ * zp1_;                              \
    a10 += zw1_ * zp0_; a11 += zw1_ * zp1_;                              \
    a20 += zw2_ * zp0_; a21 += zw2_ * zp1_;                              \
    a30 += zw3_ * zp0_; a31 += zw3_ * zp1_;                              \
  } while (0)

  for (int j = beg + wave; j < end; j += 16) {
    // 4 independent edges per iteration (j, j+4, j+8, j+12), tails clamped
    // to a valid index with weight forced to 0.
    bool v1 = (j + 4) < end, v2 = (j + 8) < end, v3 = (j + 12) < end;
    int2 e0 = ed[j];
    int2 e1 = ed[v1 ? j + 4 : j];
    int2 e2 = ed[v2 ? j + 8 : j];
    int2 e3 = ed[v3 ? j + 12 : j];
    unsigned u0 = xb[(size_t)(e0.x & 0x0FFFFFFF) * 64 + lane];
    unsigned u1 = xb[(size_t)(e1.x & 0x0FFFFFFF) * 64 + lane];
    unsigned u2 = xb[(size_t)(e2.x & 0x0FFFFFFF) * 64 + lane];
    unsigned u3 = xb[(size_t)(e3.x & 0x0FFFFFFF) * 64 + lane];
    float wgt0 = __int_as_float(e0.y);
    float wgt1 = v1 ? __int_as_float(e1.y) : 0.f;
    float wgt2 = v2 ? __int_as_float(e2.y) : 0.f;
    float wgt3 = v3 ? __int_as_float(e3.y) : 0.f;
    ACCW(e0, u0, wgt0);
    ACCW(e1, u1, wgt1);
    ACCW(e2, u2, wgt2);
    ACCW(e3, u3, wgt3);
  }
#undef ACCW

  if (wave) {
    part[wave - 1][0][lane] = make_float2(a00, a01);
    part[wave - 1][1][lane] = make_float2(a10, a11);
    part[wave - 1][2][lane] = make_float2(a20, a21);
    part[wave - 1][3][lane] = make_float2(a30, a31);
  }
  __syncthreads();
  if (wave == 0) {
#pragma unroll
    for (int w = 0; w < 3; ++w) {
      float2 q0 = part[w][0][lane], q1 = part[w][1][lane];
      float2 q2 = part[w][2][lane], q3 = part[w][3][lane];
      a00 += q0.x; a01 += q0.y;
      a10 += q1.x; a11 += q1.y;
      a20 += q2.x; a21 += q2.y;
      a30 += q3.x; a31 += q3.y;
    }
    unsigned* row = g + (size_t)node * 320;
    row[0 * 64 + lane] = pkbf(a00, a01);
    row[1 * 64 + lane] = pkbf(a10, a11);
    row[2 * 64 + lane] = pkbf(a20, a21);
    row[3 * 64 + lane] = pkbf(a30, a31);
    row[256 + lane] = xb[(size_t)node * 64 + lane];  // root/self
  }
}

// ---------------------------------------------------------------------------
// GEMM (R5-verified): out[m][n] = A[m][:] @ wt[n][:] + bias[n].
// BM=32 rows/block, 512 thr (8 waves). Whole-row A in XOR-swizzled LDS;
// B per-wave from global (L2-resident wt); zero barriers in the K-loop.
// ---------------------------------------------------------------------------
template <int BF16OUT>
__global__ __launch_bounds__(512, 2) void gemm_kernel(
    const unsigned* __restrict__ gA,   // [NN][320] u32
    const __bf16* __restrict__ wt, const float* __restrict__ bias,
    float* __restrict__ outf, __bf16* __restrict__ outb) {
  __shared__ unsigned As32[BM * 320];  // 40 KB
  int tid = threadIdx.x;
  int wave = tid >> 6, lane = tid & 63;
  int wr = wave >> 2, wc = wave & 3;
  int m0 = blockIdx.x * BM;
  int rl = wr * 16 + (lane & 15);
  int kfe = (lane >> 4) * 8;
  int c0 = wc * 32 + (lane & 15);
  const f32x4 zz = {0.f, 0.f, 0.f, 0.f};

  // ---- layout probe (R4/R5-verified): decode acc slot -> (row,col) ----
  unsigned rowpack = 0, colpack0 = 0, colpack1 = 0;
  {
    if (tid < 256) {
      int row = tid >> 3;
      int wl = (tid & 7) * 2;
      unsigned val = pkbf((float)row * 0.03125f, (float)row * 0.03125f);
      int sw2 = (row & 7) << 2;
      As32[row * 320 + (wl ^ sw2)] = val;
      As32[row * 320 + ((wl + 1) ^ sw2)] = val;
    }
    __syncthreads();
    const char* Arow = (const char*)As32 + rl * 1280;
    int swb = (rl & 7) << 4;
    bf16x8 pa = *(const bf16x8*)(Arow + ((kfe * 2) ^ swb));
    bf16x8 ones, bp0, bp1;
#pragma unroll
    for (int i = 0; i < 8; ++i) ones[i] = (__bf16)1.0f;
    __bf16 c0v = (__bf16)((float)c0 * 0.0078125f);
    __bf16 c1v = (__bf16)((float)(c0 + 16) * 0.0078125f);
#pragma unroll
    for (int i = 0; i < 8; ++i) { bp0[i] = c0v; bp1[i] = c1v; }
    f32x4 P1 = __builtin_amdgcn_mfma_f32_16x16x32_bf16(pa, ones, zz, 0, 0, 0);
    f32x4 P2a = __builtin_amdgcn_mfma_f32_16x16x32_bf16(ones, bp0, zz, 0, 0, 0);
    f32x4 P2b = __builtin_amdgcn_mfma_f32_16x16x32_bf16(ones, bp1, zz, 0, 0, 0);
#pragma unroll
    for (int j = 0; j < 4; ++j) {
      rowpack |= ((unsigned)(int)(P1[j] + 0.5f)) << (8 * j);
      colpack0 |= ((unsigned)(int)(P2a[j] * 4.0f + 0.5f)) << (8 * j);
      colpack1 |= ((unsigned)(int)(P2b[j] * 4.0f + 0.5f)) << (8 * j);
    }
    __syncthreads();
  }

  // ---- load A tile [32][640] bf16 from g, swizzled (16B chunks) ----
  {
    int row = tid >> 4;       // 32 rows, 16 threads each
    int c16 = tid & 15;
    const uint4* srcp = (const uint4*)(gA + (size_t)(m0 + row) * 320);
    unsigned sw2 = (row & 7) << 2;
    unsigned* dstw = As32 + row * 320;
#pragma unroll
    for (int jj = 0; jj < 5; ++jj) {
      int chunk = c16 + 16 * jj;        // 80 chunks of 16B per row
      uint4 v = srcp[chunk];
      *(uint4*)(dstw + ((chunk * 4) ^ sw2)) = v;
    }
  }
  __syncthreads();

  // ---- K-loop: zero barriers ----
  f32x4 acc0 = zz, acc1 = zz;
  const __bf16* w0p = wt + (size_t)c0 * KTOT + kfe;
  const __bf16* w1p = w0p + 16 * KTOT;
  const char* Arow = (const char*)As32 + rl * 1280;
  int swb = (rl & 7) << 4;
#pragma unroll
  for (int step = 0; step < 20; ++step) {
    int b = (step * 64 + kfe * 2) ^ swb;
    bf16x8 a = *(const bf16x8*)(Arow + b);
    bf16x8 b0 = *(const bf16x8*)(w0p + step * 32);
    bf16x8 b1 = *(const bf16x8*)(w1p + step * 32);
    acc0 = __builtin_amdgcn_mfma_f32_16x16x32_bf16(a, b0, acc0, 0, 0, 0);
    acc1 = __builtin_amdgcn_mfma_f32_16x16x32_bf16(a, b1, acc1, 0, 0, 0);
  }

  // ---- epilogue (R4/R5-verified) ----
#pragma unroll
  for (int j = 0; j < 4; ++j) {
    int rloc = (int)((rowpack >> (8 * j)) & 255u);
    size_t m = (size_t)(m0 + rloc);
    {
      int col = (int)((colpack0 >> (8 * j)) & 255u);
      float v = acc0[j] + bias[col];
      if (BF16OUT) outb[m * FD + col] = (__bf16)fmaxf(v, 0.f);
      else outf[m * FD + col] = v;
    }
    {
      int col = (int)((colpack1 >> (8 * j)) & 255u);
      float v = acc1[j] + bias[col];
      if (BF16OUT) outb[m * FD + col] = (__bf16)fmaxf(v, 0.f);
      else outf[m * FD + col] = v;
    }
  }
}

extern "C" void kernel_launch(void* const* d_in, const int* in_sizes, int n_in,
                              void* d_out, int out_size, void* d_ws, size_t ws_size,
                              hipStream_t stream) {
  const float* x  = (const float*)d_in[0];
  const int*   ei = (const int*)d_in[1];
  const int*   et = (const int*)d_in[2];
  const float* ew = (const float*)d_in[3];
  const float* W1 = (const float*)d_in[4];
  const float* r1 = (const float*)d_in[5];
  const float* b1 = (const float*)d_in[6];
  const float* W2 = (const float*)d_in[7];
  const float* r2 = (const float*)d_in[8];
  const float* b2 = (const float*)d_in[9];
  float* out = (float*)d_out;
  const int* src = ei;
  const int* dst = ei + NE;

  char* w = (char*)d_ws;
  size_t o = 0;
  auto take = [&](size_t bytes) -> char* {
    char* p = w + o;
    o += (bytes + 255) & ~(size_t)255;
    return p;
  };
  unsigned* mm  = (unsigned*)take(8);
  int* deg      = (int*)take((size_t)NN * 4);
  int* offs     = (int*)take((size_t)(NN + 1) * 4);
  int* cursor   = (int*)take((size_t)NN * 4);
  int2* ed      = (int2*)take((size_t)(NE + 8) * 8);
  unsigned* xb  = (unsigned*)take((size_t)NN * 64 * 4);
  unsigned* g   = (unsigned*)take((size_t)NN * 320 * 4);
  __bf16* h1    = (__bf16*)take((size_t)NN * FD * 2);
  __bf16* wt1   = (__bf16*)take((size_t)FD * KTOT * 2);
  __bf16* wt2   = (__bf16*)take((size_t)FD * KTOT * 2);
  (void)ws_size; (void)n_in; (void)in_sizes; (void)out_size;

  hipLaunchKernelGGL(prep_kernel, dim3((NN * FD / 4 + 255) / 256), dim3(256), 0, stream,
                     mm, deg, x, xb, W1, r1, W2, r2, wt1, wt2);
  hipLaunchKernelGGL(histmm_kernel, dim3(512), dim3(256), 0, stream, dst, ew, deg, mm);
  hipLaunchKernelGGL(scan_kernel, dim3(1), dim3(1024), 0, stream, deg, offs, cursor);
  hipLaunchKernelGGL(fill_kernel, dim3((NE + 255) / 256), dim3(256), 0, stream,
                     src, dst, et, ew, mm, cursor, ed);
  // layer 1
  hipLaunchKernelGGL(aggregate_kernel, dim3(NN), dim3(256), 0, stream, xb, offs, ed, g);
  hipLaunchKernelGGL((gemm_kernel<1>), dim3(NN / BM), dim3(512), 0, stream,
                     g, wt1, b1, (float*)nullptr, h1);
  // layer 2
  hipLaunchKernelGGL(aggregate_kernel, dim3(NN), dim3(256), 0, stream,
                     (const unsigned*)h1, offs, ed, g);
  hipLaunchKernelGGL((gemm_kernel<0>), dim3(NN / BM), dim3(512), 0, stream,
                     g, wt2, b2, out, (__bf16*)nullptr);
}

// Round 9
// 194.935 us; speedup vs baseline: 1.0426x; 1.0426x over previous
//
#include <hip/hip_runtime.h>
#include <hip/hip_cooperative_groups.h>

namespace cg = cooperative_groups;

#define NN 20000
#define NE 320000
#define FD 128
#define KTOT 640          // 4*128 relations + 128 root/self
#define NBLK 512
#define NTHR 256
#define GSZ (NBLK * NTHR) // 131072
#define NWAVES (NBLK * 4) // 2048
#define NTILE 625         // NN / 32
#define CH 40             // nodes per block in scan (512*40 = 20480 >= NN)

typedef float f32x4 __attribute__((ext_vector_type(4)));
typedef __bf16 bf16x8 __attribute__((ext_vector_type(8)));

__device__ __forceinline__ unsigned f2ord(float f) {
  unsigned u = __float_as_uint(f);
  return (u & 0x80000000u) ? ~u : (u | 0x80000000u);
}
__device__ __forceinline__ float ord2f(unsigned u) {
  return (u & 0x80000000u) ? __uint_as_float(u & 0x7FFFFFFFu) : __uint_as_float(~u);
}
__device__ __forceinline__ unsigned pkbf(float a, float b) {
  union { __bf16 h[2]; unsigned u; } p;
  p.h[0] = (__bf16)a; p.h[1] = (__bf16)b; return p.u;
}

// ---- aggregation phase: 1 wave per node, grid-stride, 4 gather chains ----
__device__ __forceinline__ void agg_phase(
    const unsigned* __restrict__ xb, const int* __restrict__ offs,
    const int2* __restrict__ ed, unsigned* __restrict__ g, int nwaves) {
  int wid = blockIdx.x * 4 + (threadIdx.x >> 6);
  int lane = threadIdx.x & 63;
#define ACCW(E, U, WV)                                                   \
  do {                                                                   \
    float zp0_ = __uint_as_float((U) << 16);                             \
    float zp1_ = __uint_as_float((U) & 0xFFFF0000u);                     \
    unsigned zr_ = ((unsigned)(E).x) >> 28;                              \
    float zw0_ = (zr_ == 0) ? (WV) : 0.f;                                \
    float zw1_ = (zr_ == 1) ? (WV) : 0.f;                                \
    float zw2_ = (zr_ == 2) ? (WV) : 0.f;                                \
    float zw3_ = (zr_ == 3) ? (WV) : 0.f;                                \
    a00 += zw0_ * zp0_; a01 += zw0_ * zp1_;                              \
    a10 += zw1_ * zp0_; a11 += zw1_ * zp1_;                              \
    a20 += zw2_ * zp0_; a21 += zw2_ * zp1_;                              \
    a30 += zw3_ * zp0_; a31 += zw3_ * zp1_;                              \
  } while (0)
  for (int node = wid; node < NN; node += nwaves) {
    int beg = offs[node], end = offs[node + 1];
    float a00 = 0.f, a01 = 0.f, a10 = 0.f, a11 = 0.f;
    float a20 = 0.f, a21 = 0.f, a30 = 0.f, a31 = 0.f;
    for (int j = beg; j < end; j += 4) {
      bool v1 = (j + 1) < end, v2 = (j + 2) < end, v3 = (j + 3) < end;
      int2 e0 = ed[j];
      int2 e1 = ed[v1 ? j + 1 : j];
      int2 e2 = ed[v2 ? j + 2 : j];
      int2 e3 = ed[v3 ? j + 3 : j];
      unsigned u0 = xb[(size_t)(e0.x & 0x0FFFFFFF) * 64 + lane];
      unsigned u1 = xb[(size_t)(e1.x & 0x0FFFFFFF) * 64 + lane];
      unsigned u2 = xb[(size_t)(e2.x & 0x0FFFFFFF) * 64 + lane];
      unsigned u3 = xb[(size_t)(e3.x & 0x0FFFFFFF) * 64 + lane];
      float wgt0 = __int_as_float(e0.y);
      float wgt1 = v1 ? __int_as_float(e1.y) : 0.f;
      float wgt2 = v2 ? __int_as_float(e2.y) : 0.f;
      float wgt3 = v3 ? __int_as_float(e3.y) : 0.f;
      ACCW(e0, u0, wgt0);
      ACCW(e1, u1, wgt1);
      ACCW(e2, u2, wgt2);
      ACCW(e3, u3, wgt3);
    }
    unsigned* row = g + (size_t)node * 320;
    row[0 * 64 + lane] = pkbf(a00, a01);
    row[1 * 64 + lane] = pkbf(a10, a11);
    row[2 * 64 + lane] = pkbf(a20, a21);
    row[3 * 64 + lane] = pkbf(a30, a31);
    row[256 + lane] = xb[(size_t)node * 64 + lane];  // root/self
  }
#undef ACCW
}

// ---- GEMM phase: 256 thr / 4 waves, grid-stride over 625 BM=32 tiles ----
__device__ __forceinline__ void gemm_phase(
    unsigned* As32, const unsigned* __restrict__ gbuf,
    const __bf16* __restrict__ wt, const float* __restrict__ bias,
    float* __restrict__ outf, __bf16* __restrict__ outb,
    unsigned rowpack, const unsigned* colpack) {
  int tid = threadIdx.x;
  int wave = tid >> 6, lane = tid & 63;
  int wr = wave >> 1, wc = wave & 1;
  int rl = wr * 16 + (lane & 15);
  int kfe = (lane >> 4) * 8;
  const f32x4 zz = {0.f, 0.f, 0.f, 0.f};
  for (int t = blockIdx.x; t < NTILE; t += NBLK) {
    __syncthreads();
    int m0 = t * 32;
    {
      int row = tid >> 3;
      const uint4* srcp = (const uint4*)(gbuf + (size_t)(m0 + row) * 320);
      unsigned sw2 = (row & 7) << 2;
      unsigned* dstw = As32 + row * 320;
#pragma unroll
      for (int jj = 0; jj < 10; ++jj) {
        int chunk = (tid & 7) + 8 * jj;
        uint4 v = srcp[chunk];
        *(uint4*)(dstw + ((chunk * 4) ^ sw2)) = v;
      }
    }
    __syncthreads();
    f32x4 acc0 = zz, acc1 = zz, acc2 = zz, acc3 = zz;
    const char* Arow = (const char*)As32 + rl * 1280;
    int swb = (rl & 7) << 4;
    const __bf16* wp0 = wt + (size_t)(wc * 64 + (lane & 15)) * KTOT + kfe;
    const __bf16* wp1 = wp0 + 16 * KTOT;
    const __bf16* wp2 = wp0 + 32 * KTOT;
    const __bf16* wp3 = wp0 + 48 * KTOT;
#pragma unroll
    for (int step = 0; step < 20; ++step) {
      bf16x8 a = *(const bf16x8*)(Arow + ((step * 64 + kfe * 2) ^ swb));
      bf16x8 bv0 = *(const bf16x8*)(wp0 + step * 32);
      bf16x8 bv1 = *(const bf16x8*)(wp1 + step * 32);
      bf16x8 bv2 = *(const bf16x8*)(wp2 + step * 32);
      bf16x8 bv3 = *(const bf16x8*)(wp3 + step * 32);
      acc0 = __builtin_amdgcn_mfma_f32_16x16x32_bf16(a, bv0, acc0, 0, 0, 0);
      acc1 = __builtin_amdgcn_mfma_f32_16x16x32_bf16(a, bv1, acc1, 0, 0, 0);
      acc2 = __builtin_amdgcn_mfma_f32_16x16x32_bf16(a, bv2, acc2, 0, 0, 0);
      acc3 = __builtin_amdgcn_mfma_f32_16x16x32_bf16(a, bv3, acc3, 0, 0, 0);
    }
#define EPI(ACC, FN)                                                          \
    do {                                                                      \
      _Pragma("unroll")                                                       \
      for (int j = 0; j < 4; ++j) {                                           \
        int rloc = (int)((rowpack >> (8 * j)) & 255u);                        \
        int col = (int)((colpack[FN] >> (8 * j)) & 255u);                     \
        size_t m = (size_t)(m0 + rloc);                                       \
        float v = (ACC)[j] + bias[col];                                       \
        if (outb) outb[m * FD + col] = (__bf16)fmaxf(v, 0.f);                 \
        else outf[m * FD + col] = v;                                          \
      }                                                                       \
    } while (0)
    EPI(acc0, 0); EPI(acc1, 1); EPI(acc2, 2); EPI(acc3, 3);
#undef EPI
  }
}

// min-2-waves/EU => VGPR<=256 => 2 blocks/CU => 512-block coop launch is legal
__global__ __launch_bounds__(NTHR, 2) void mega_kernel(
    const float* __restrict__ x, const int* __restrict__ ei,
    const int* __restrict__ et, const float* __restrict__ ew,
    const float* __restrict__ W1, const float* __restrict__ r1,
    const float* __restrict__ b1, const float* __restrict__ W2,
    const float* __restrict__ r2, const float* __restrict__ b2,
    float* __restrict__ out, char* __restrict__ ws) {
  cg::grid_group grid = cg::this_grid();
  __shared__ unsigned slds[10240];  // 40 KB, aliased per phase
  const int* srcv = ei;
  const int* dstv = ei + NE;
  int tid = threadIdx.x, bid = blockIdx.x;
  int gtid = bid * NTHR + tid;

  size_t o = 0;
  auto take = [&](size_t bytes) -> char* {
    char* p = ws + o;
    o += (bytes + 255) & ~(size_t)255;
    return p;
  };
  unsigned* mm   = (unsigned*)take(8);
  int* deg       = (int*)take((size_t)NN * 4);
  int* offs      = (int*)take((size_t)(NN + 1) * 4);
  int* cursor    = (int*)take((size_t)NN * 4);
  int* blocksum  = (int*)take((size_t)NBLK * 4);
  int2* ed       = (int2*)take((size_t)(NE + 8) * 8);
  unsigned* xb   = (unsigned*)take((size_t)NN * 64 * 4);
  unsigned* g1   = (unsigned*)take((size_t)NN * 320 * 4);
  unsigned* g2   = (unsigned*)take((size_t)NN * 320 * 4);
  unsigned* h1   = (unsigned*)take((size_t)NN * 64 * 4);
  __bf16* wt1    = (__bf16*)take((size_t)FD * KTOT * 2);
  __bf16* wt2    = (__bf16*)take((size_t)FD * KTOT * 2);

  // ===== P0: prep =====
  if (gtid == 0) { mm[0] = 0xFFFFFFFFu; mm[1] = 0u; }
  for (int i = gtid; i < NN; i += GSZ) deg[i] = 0;
  for (int i = gtid; i < 2 * FD * KTOT; i += GSZ) {
    int which = i / (FD * KTOT);
    int rem = i % (FD * KTOT);
    int n = rem / KTOT, k = rem % KTOT;
    const float* W = which ? W2 : W1;
    const float* rt = which ? r2 : r1;
    float v = (k < 512) ? W[(size_t)k * FD + n] : rt[(size_t)(k - 512) * FD + n];
    (which ? wt2 : wt1)[rem] = (__bf16)v;
  }
  for (int i = gtid; i < NN * FD / 4; i += GSZ) {
    float4 v = *(const float4*)(x + (size_t)i * 4);
    uint2 p;
    p.x = pkbf(v.x, v.y);
    p.y = pkbf(v.z, v.w);
    *(uint2*)(xb + (size_t)i * 2) = p;
  }
  __threadfence();
  grid.sync();

  // ===== P1: histogram + minmax =====
  {
    unsigned lmn = 0xFFFFFFFFu, lmx = 0u;
    for (int i = gtid; i < NE; i += GSZ) {
      atomicAdd(&deg[dstv[i]], 1);
      unsigned ov = f2ord(ew[i]);
      lmn = (ov < lmn) ? ov : lmn;
      lmx = (ov > lmx) ? ov : lmx;
    }
    slds[tid] = lmn; slds[256 + tid] = lmx;
    __syncthreads();
    for (int s = 128; s > 0; s >>= 1) {
      if (tid < s) {
        unsigned a = slds[tid], b = slds[tid + s];
        slds[tid] = (b < a) ? b : a;
        unsigned c = slds[256 + tid], d = slds[256 + tid + s];
        slds[256 + tid] = (d > c) ? d : c;
      }
      __syncthreads();
    }
    if (tid == 0) { atomicMin(&mm[0], slds[0]); atomicMax(&mm[1], slds[256]); }
  }
  __threadfence();
  grid.sync();

  // ===== P2a: block-local degree prefix =====
  if (tid < CH) {
    int node = bid * CH + tid;
    slds[tid] = (node < NN) ? (unsigned)deg[node] : 0u;
  }
  __syncthreads();
  if (tid == 0) {
    unsigned s = 0;
#pragma unroll 1
    for (int i = 0; i < CH; ++i) { unsigned d = slds[i]; slds[i] = s; s += d; }
    blocksum[bid] = (int)s;
  }
  __threadfence();
  grid.sync();

  // ===== P2b: cross-block prefix + offs/cursor =====
  {
    unsigned v = 0;
    if (tid < bid) v += (unsigned)blocksum[tid];
    if (tid + 256 < bid) v += (unsigned)blocksum[tid + 256];
#pragma unroll
    for (int s = 32; s > 0; s >>= 1) v += __shfl_xor(v, s, 64);
    if ((tid & 63) == 0) slds[1024 + (tid >> 6)] = v;
    __syncthreads();
    if (tid == 0) slds[1028] = slds[1024] + slds[1025] + slds[1026] + slds[1027];
    __syncthreads();
    unsigned base = slds[1028];
    if (tid < CH) {
      int node = bid * CH + tid;
      if (node < NN) {
        int ov = (int)(base + slds[tid]);
        offs[node] = ov;
        cursor[node] = ov;
      }
    }
    if (gtid == 0) offs[NN] = NE;
  }
  __threadfence();
  grid.sync();

  // ===== P3: fill CSR =====
  {
    float mn = ord2f(mm[0]), mx = ord2f(mm[1]);
    float inv = 1.0f / (mx - mn + 1e-8f);
    for (int e = gtid; e < NE; e += GSZ) {
      int d = dstv[e];
      int pos = atomicAdd(&cursor[d], 1);
      ed[pos] = make_int2(srcv[e] | (et[e] << 28), __float_as_int((ew[e] - mn) * inv));
    }
  }
  __threadfence();
  grid.sync();

  // ===== P4: aggregate layer 1 =====
  agg_phase(xb, offs, ed, g1, NWAVES);
  __threadfence();
  grid.sync();

  // ---- layout probe (once, reused for both GEMMs) ----
  unsigned rowpack = 0, colpack[4];
  {
    unsigned* As32 = slds;
    int row = tid >> 3, wl = (tid & 7) * 2;
    unsigned val = pkbf((float)row * 0.03125f, (float)row * 0.03125f);
    int sw2 = (row & 7) << 2;
    As32[row * 320 + (wl ^ sw2)] = val;
    As32[row * 320 + ((wl + 1) ^ sw2)] = val;
    __syncthreads();
    int wave = tid >> 6, lane = tid & 63;
    int wr = wave >> 1, wc = wave & 1;
    int rl = wr * 16 + (lane & 15);
    int kfe = (lane >> 4) * 8;
    const f32x4 zz = {0.f, 0.f, 0.f, 0.f};
    const char* Arow = (const char*)As32 + rl * 1280;
    int swb = (rl & 7) << 4;
    bf16x8 pa = *(const bf16x8*)(Arow + ((kfe * 2) ^ swb));
    bf16x8 ones;
#pragma unroll
    for (int i = 0; i < 8; ++i) ones[i] = (__bf16)1.0f;
    f32x4 P1 = __builtin_amdgcn_mfma_f32_16x16x32_bf16(pa, ones, zz, 0, 0, 0);
#pragma unroll
    for (int j = 0; j < 4; ++j)
      rowpack |= ((unsigned)(int)(P1[j] + 0.5f)) << (8 * j);
#pragma unroll
    for (int fn = 0; fn < 4; ++fn) {
      int cf = wc * 64 + fn * 16 + (lane & 15);
      __bf16 cv = (__bf16)((float)cf * 0.0078125f);
      bf16x8 bp;
#pragma unroll
      for (int i = 0; i < 8; ++i) bp[i] = cv;
      f32x4 P2 = __builtin_amdgcn_mfma_f32_16x16x32_bf16(ones, bp, zz, 0, 0, 0);
      unsigned cp = 0;
#pragma unroll
      for (int j = 0; j < 4; ++j)
        cp |= ((unsigned)(int)(P2[j] * 4.0f + 0.5f)) << (8 * j);
      colpack[fn] = cp;
    }
  }

  // ===== P5: GEMM layer 1 -> h1 (bf16, relu) =====
  gemm_phase(slds, g1, wt1, b1, nullptr, (__bf16*)h1, rowpack, colpack);
  __threadfence();
  grid.sync();

  // ===== P6: aggregate layer 2 =====
  agg_phase(h1, offs, ed, g2, NWAVES);
  __threadfence();
  grid.sync();

  // ===== P7: GEMM layer 2 -> out (f32) =====
  gemm_phase(slds, g2, wt2, b2, out, nullptr, rowpack, colpack);
}

// ======================= fallback path (R5-proven, 192 µs) ==================
__global__ void prep_kernel(unsigned* mm, int* deg,
                            const float* __restrict__ x, unsigned* __restrict__ xb,
                            const float* __restrict__ W1, const float* __restrict__ r1,
                            const float* __restrict__ W2, const float* __restrict__ r2,
                            __bf16* __restrict__ wt1, __bf16* __restrict__ wt2) {
  int i = blockIdx.x * blockDim.x + threadIdx.x;
  if (i == 0) { mm[0] = 0xFFFFFFFFu; mm[1] = 0u; }
  if (i < NN) deg[i] = 0;
  if (i < 2 * FD * KTOT) {
    int which = i / (FD * KTOT);
    int rem = i % (FD * KTOT);
    int n = rem / KTOT, k = rem % KTOT;
    const float* W = which ? W2 : W1;
    const float* rt = which ? r2 : r1;
    float v = (k < 512) ? W[(size_t)k * FD + n] : rt[(size_t)(k - 512) * FD + n];
    (which ? wt2 : wt1)[rem] = (__bf16)v;
  }
  if (i < NN * FD / 4) {
    float4 v = *(const float4*)(x + (size_t)i * 4);
    uint2 p;
    p.x = pkbf(v.x, v.y);
    p.y = pkbf(v.z, v.w);
    *(uint2*)(xb + (size_t)i * 2) = p;
  }
}

__global__ void histmm_kernel(const int* __restrict__ dst, const float* __restrict__ ew,
                              int* deg, unsigned* mm) {
  __shared__ unsigned smn[256], smx[256];
  unsigned lmn = 0xFFFFFFFFu, lmx = 0u;
  for (int i = blockIdx.x * blockDim.x + threadIdx.x; i < NE; i += gridDim.x * blockDim.x) {
    atomicAdd(&deg[dst[i]], 1);
    unsigned ov = f2ord(ew[i]);
    lmn = (ov < lmn) ? ov : lmn;
    lmx = (ov > lmx) ? ov : lmx;
  }
  smn[threadIdx.x] = lmn; smx[threadIdx.x] = lmx;
  __syncthreads();
  for (int s = 128; s > 0; s >>= 1) {
    if (threadIdx.x < s) {
      unsigned a = smn[threadIdx.x], b = smn[threadIdx.x + s];
      smn[threadIdx.x] = (b < a) ? b : a;
      unsigned c = smx[threadIdx.x], d = smx[threadIdx.x + s];
      smx[threadIdx.x] = (d > c) ? d : c;
    }
    __syncthreads();
  }
  if (threadIdx.x == 0) { atomicMin(&mm[0], smn[0]); atomicMax(&mm[1], smx[0]); }
}

__global__ void scan_kernel(const int* __restrict__ deg, int* offs, int* cursor) {
  __shared__ int part[1024];
  const int CHS = (NN + 1023) / 1024;
  int t = threadIdx.x;
  int b = t * CHS;
  int e = (b + CHS < NN) ? (b + CHS) : NN;
  int s = 0;
  for (int i = b; i < e; ++i) s += deg[i];
  part[t] = s;
  __syncthreads();
  for (int off = 1; off < 1024; off <<= 1) {
    int v = part[t];
    int add = (t >= off) ? part[t - off] : 0;
    __syncthreads();
    part[t] = v + add;
    __syncthreads();
  }
  int excl = (t == 0) ? 0 : part[t - 1];
  for (int i = b; i < e; ++i) { offs[i] = excl; cursor[i] = excl; excl += deg[i]; }
  if (t == 1023) offs[NN] = part[1023];
}

__global__ void fill_kernel(const int* __restrict__ src, const int* __restrict__ dst,
                            const int* __restrict__ et, const float* __restrict__ ew,
                            const unsigned* __restrict__ mm, int* cursor,
                            int2* __restrict__ ed) {
  int e = blockIdx.x * blockDim.x + threadIdx.x;
  if (e >= NE) return;
  float mn = ord2f(mm[0]), mx = ord2f(mm[1]);
  float inv = 1.0f / (mx - mn + 1e-8f);
  int d = dst[e];
  int pos = atomicAdd(&cursor[d], 1);
  ed[pos] = make_int2(src[e] | (et[e] << 28), __float_as_int((ew[e] - mn) * inv));
}

__global__ __launch_bounds__(256) void agg_fb(
    const unsigned* __restrict__ xb, const int* __restrict__ offs,
    const int2* __restrict__ ed, unsigned* __restrict__ g) {
  int nwaves = (NN + 3) / 4 * 4;  // grid waves == NN here (grid = NN/4 blocks x 4 waves)
  (void)nwaves;
  int wid = (int)((blockIdx.x * blockDim.x + threadIdx.x) >> 6);
  if (wid >= NN) return;
  int lane = threadIdx.x & 63;
  // reuse mega's per-node body with nwaves > NN so loop runs exactly once
  agg_phase(xb, offs, ed, g, 1 << 30);
}

template <int BF16OUT>
__global__ __launch_bounds__(512, 2) void gemm_fb(
    const unsigned* __restrict__ gA, const __bf16* __restrict__ wt,
    const float* __restrict__ bias, float* __restrict__ outf,
    __bf16* __restrict__ outb) {
  __shared__ unsigned As32[32 * 320];
  int tid = threadIdx.x;
  int wave = tid >> 6, lane = tid & 63;
  int wr = wave >> 2, wc = wave & 3;
  int m0 = blockIdx.x * 32;
  int rl = wr * 16 + (lane & 15);
  int kfe = (lane >> 4) * 8;
  int c0 = wc * 32 + (lane & 15);
  const f32x4 zz = {0.f, 0.f, 0.f, 0.f};
  unsigned rowpack = 0, colpack0 = 0, colpack1 = 0;
  {
    if (tid < 256) {
      int row = tid >> 3;
      int wl = (tid & 7) * 2;
      unsigned val = pkbf((float)row * 0.03125f, (float)row * 0.03125f);
      int sw2 = (row & 7) << 2;
      As32[row * 320 + (wl ^ sw2)] = val;
      As32[row * 320 + ((wl + 1) ^ sw2)] = val;
    }
    __syncthreads();
    const char* Arow = (const char*)As32 + rl * 1280;
    int swb = (rl & 7) << 4;
    bf16x8 pa = *(const bf16x8*)(Arow + ((kfe * 2) ^ swb));
    bf16x8 ones, bp0, bp1;
#pragma unroll
    for (int i = 0; i < 8; ++i) ones[i] = (__bf16)1.0f;
    __bf16 c0v = (__bf16)((float)c0 * 0.0078125f);
    __bf16 c1v = (__bf16)((float)(c0 + 16) * 0.0078125f);
#pragma unroll
    for (int i = 0; i < 8; ++i) { bp0[i] = c0v; bp1[i] = c1v; }
    f32x4 P1 = __builtin_amdgcn_mfma_f32_16x16x32_bf16(pa, ones, zz, 0, 0, 0);
    f32x4 P2a = __builtin_amdgcn_mfma_f32_16x16x32_bf16(ones, bp0, zz, 0, 0, 0);
    f32x4 P2b = __builtin_amdgcn_mfma_f32_16x16x32_bf16(ones, bp1, zz, 0, 0, 0);
#pragma unroll
    for (int j = 0; j < 4; ++j) {
      rowpack |= ((unsigned)(int)(P1[j] + 0.5f)) << (8 * j);
      colpack0 |= ((unsigned)(int)(P2a[j] * 4.0f + 0.5f)) << (8 * j);
      colpack1 |= ((unsigned)(int)(P2b[j] * 4.0f + 0.5f)) << (8 * j);
    }
    __syncthreads();
  }
  {
    int row = tid >> 4;
    int c16 = tid & 15;
    const uint4* srcp = (const uint4*)(gA + (size_t)(m0 + row) * 320);
    unsigned sw2 = (row & 7) << 2;
    unsigned* dstw = As32 + row * 320;
#pragma unroll
    for (int jj = 0; jj < 5; ++jj) {
      int chunk = c16 + 16 * jj;
      uint4 v = srcp[chunk];
      *(uint4*)(dstw + ((chunk * 4) ^ sw2)) = v;
    }
  }
  __syncthreads();
  f32x4 acc0 = zz, acc1 = zz;
  const __bf16* w0p = wt + (size_t)c0 * KTOT + kfe;
  const __bf16* w1p = w0p + 16 * KTOT;
  const char* Arow = (const char*)As32 + rl * 1280;
  int swb = (rl & 7) << 4;
#pragma unroll
  for (int step = 0; step < 20; ++step) {
    int b = (step * 64 + kfe * 2) ^ swb;
    bf16x8 a = *(const bf16x8*)(Arow + b);
    bf16x8 b0 = *(const bf16x8*)(w0p + step * 32);
    bf16x8 b1 = *(const bf16x8*)(w1p + step * 32);
    acc0 = __builtin_amdgcn_mfma_f32_16x16x32_bf16(a, b0, acc0, 0, 0, 0);
    acc1 = __builtin_amdgcn_mfma_f32_16x16x32_bf16(a, b1, acc1, 0, 0, 0);
  }
#pragma unroll
  for (int j = 0; j < 4; ++j) {
    int rloc = (int)((rowpack >> (8 * j)) & 255u);
    size_t m = (size_t)(m0 + rloc);
    {
      int col = (int)((colpack0 >> (8 * j)) & 255u);
      float v = acc0[j] + bias[col];
      if (BF16OUT) outb[m * FD + col] = (__bf16)fmaxf(v, 0.f);
      else outf[m * FD + col] = v;
    }
    {
      int col = (int)((colpack1 >> (8 * j)) & 255u);
      float v = acc1[j] + bias[col];
      if (BF16OUT) outb[m * FD + col] = (__bf16)fmaxf(v, 0.f);
      else outf[m * FD + col] = v;
    }
  }
}

extern "C" void kernel_launch(void* const* d_in, const int* in_sizes, int n_in,
                              void* d_out, int out_size, void* d_ws, size_t ws_size,
                              hipStream_t stream) {
  const float* x  = (const float*)d_in[0];
  const int*   ei = (const int*)d_in[1];
  const int*   et = (const int*)d_in[2];
  const float* ew = (const float*)d_in[3];
  const float* W1 = (const float*)d_in[4];
  const float* r1 = (const float*)d_in[5];
  const float* b1 = (const float*)d_in[6];
  const float* W2 = (const float*)d_in[7];
  const float* r2 = (const float*)d_in[8];
  const float* b2 = (const float*)d_in[9];
  float* out = (float*)d_out;
  char* ws = (char*)d_ws;
  (void)ws_size; (void)n_in; (void)in_sizes; (void)out_size;

  // carve (must mirror mega_kernel's internal carve)
  size_t o = 0;
  auto take = [&](size_t bytes) -> char* {
    char* p = ws + o;
    o += (bytes + 255) & ~(size_t)255;
    return p;
  };
  unsigned* mm   = (unsigned*)take(8);
  int* deg       = (int*)take((size_t)NN * 4);
  int* offs      = (int*)take((size_t)(NN + 1) * 4);
  int* cursor    = (int*)take((size_t)NN * 4);
  int* blocksum  = (int*)take((size_t)NBLK * 4);
  int2* ed       = (int2*)take((size_t)(NE + 8) * 8);
  unsigned* xb   = (unsigned*)take((size_t)NN * 64 * 4);
  unsigned* g1   = (unsigned*)take((size_t)NN * 320 * 4);
  unsigned* g2   = (unsigned*)take((size_t)NN * 320 * 4);
  unsigned* h1   = (unsigned*)take((size_t)NN * 64 * 4);
  __bf16* wt1    = (__bf16*)take((size_t)FD * KTOT * 2);
  __bf16* wt2    = (__bf16*)take((size_t)FD * KTOT * 2);
  (void)blocksum; (void)g2;

  int maxB = 0;
  hipError_t qerr = hipOccupancyMaxActiveBlocksPerMultiprocessor(
      &maxB, (const void*)mega_kernel, NTHR, 0);
  bool coop = (qerr == hipSuccess && maxB >= 2);
  if (coop) {
    void* args[] = {(void*)&x,  (void*)&ei, (void*)&et, (void*)&ew,
                    (void*)&W1, (void*)&r1, (void*)&b1, (void*)&W2,
                    (void*)&r2, (void*)&b2, (void*)&out, (void*)&ws};
    coop = (hipLaunchCooperativeKernel((const void*)mega_kernel, dim3(NBLK),
                                       dim3(NTHR), args, 0, stream) == hipSuccess);
  }
  if (!coop) {
    const int* src = ei;
    const int* dst = ei + NE;
    hipLaunchKernelGGL(prep_kernel, dim3((NN * FD / 4 + 255) / 256), dim3(256), 0, stream,
                       mm, deg, x, xb, W1, r1, W2, r2, wt1, wt2);
    hipLaunchKernelGGL(histmm_kernel, dim3(512), dim3(256), 0, stream, dst, ew, deg, mm);
    hipLaunchKernelGGL(scan_kernel, dim3(1), dim3(1024), 0, stream, deg, offs, cursor);
    hipLaunchKernelGGL(fill_kernel, dim3((NE + 255) / 256), dim3(256), 0, stream,
                       src, dst, et, ew, mm, cursor, ed);
    hipLaunchKernelGGL(agg_fb, dim3(NN / 4), dim3(256), 0, stream, xb, offs, ed, g1);
    hipLaunchKernelGGL((gemm_fb<1>), dim3(NN / 32), dim3(512), 0, stream,
                       g1, wt1, b1, (float*)nullptr, (__bf16*)h1);
    hipLaunchKernelGGL(agg_fb, dim3(NN / 4), dim3(256), 0, stream,
                       (const unsigned*)h1, offs, ed, g1);
    hipLaunchKernelGGL((gemm_fb<0>), dim3(NN / 32), dim3(512), 0, stream,
                       g1, wt2, b2, out, (__bf16*)nullptr);
  }
}

// Round 10
// 162.722 us; speedup vs baseline: 1.2490x; 1.1980x over previous
//
#include <hip/hip_runtime.h>

#define NN 20000
#define NE 320000
#define FD 128
#define KTOT 640   // 4*128 (relations) + 128 (root/self)
#define NSTEP 20   // KTOT / 32

typedef float f32x4 __attribute__((ext_vector_type(4)));
typedef __bf16 bf16x4 __attribute__((ext_vector_type(4)));
typedef __bf16 bf16x8 __attribute__((ext_vector_type(8)));

__device__ __forceinline__ unsigned f2ord(float f) {
  unsigned u = __float_as_uint(f);
  return (u & 0x80000000u) ? ~u : (u | 0x80000000u);
}
__device__ __forceinline__ float ord2f(unsigned u) {
  return (u & 0x80000000u) ? __uint_as_float(u & 0x7FFFFFFFu) : __uint_as_float(~u);
}
__device__ __forceinline__ unsigned pkbf(float a, float b) {
  union { __bf16 h[2]; unsigned u; } p;
  p.h[0] = (__bf16)a; p.h[1] = (__bf16)b; return p.u;
}
// async global->LDS, 16B per lane; LDS dest is wave-uniform base (lane*16 implied)
__device__ __forceinline__ void gld16(const void* src, void* lds) {
  __builtin_amdgcn_global_load_lds(
      (const unsigned int __attribute__((address_space(1)))*)src,
      (unsigned int __attribute__((address_space(3)))*)lds, 16, 0, 0);
}

// prep: mm seed, deg zero, x->bf16 pack, both layers' wt (B^T) build
__global__ void prep_kernel(unsigned* mm, int* deg,
                            const float* __restrict__ x, unsigned* __restrict__ xb,
                            const float* __restrict__ W1, const float* __restrict__ r1,
                            const float* __restrict__ W2, const float* __restrict__ r2,
                            __bf16* __restrict__ wt1, __bf16* __restrict__ wt2) {
  int i = blockIdx.x * blockDim.x + threadIdx.x;
  if (i == 0) { mm[0] = 0xFFFFFFFFu; mm[1] = 0u; }
  if (i < NN) deg[i] = 0;
  if (i < 2 * FD * KTOT) {
    int which = i / (FD * KTOT);
    int rem = i % (FD * KTOT);
    int n = rem / KTOT, k = rem % KTOT;
    const float* W = which ? W2 : W1;
    const float* rt = which ? r2 : r1;
    float v = (k < 512) ? W[(size_t)k * FD + n] : rt[(size_t)(k - 512) * FD + n];
    (which ? wt2 : wt1)[rem] = (__bf16)v;
  }
  if (i < NN * FD / 4) {
    float4 v = *(const float4*)(x + (size_t)i * 4);
    uint2 p;
    p.x = pkbf(v.x, v.y);
    p.y = pkbf(v.z, v.w);
    *(uint2*)(xb + (size_t)i * 2) = p;
  }
}

__global__ void histmm_kernel(const int* __restrict__ dst, const float* __restrict__ ew,
                              int* deg, unsigned* mm) {
  __shared__ unsigned smn[256], smx[256];
  unsigned lmn = 0xFFFFFFFFu, lmx = 0u;
  for (int i = blockIdx.x * blockDim.x + threadIdx.x; i < NE; i += gridDim.x * blockDim.x) {
    atomicAdd(&deg[dst[i]], 1);
    unsigned o = f2ord(ew[i]);
    lmn = (o < lmn) ? o : lmn;
    lmx = (o > lmx) ? o : lmx;
  }
  smn[threadIdx.x] = lmn; smx[threadIdx.x] = lmx;
  __syncthreads();
  for (int s = 128; s > 0; s >>= 1) {
    if (threadIdx.x < s) {
      unsigned a = smn[threadIdx.x], b = smn[threadIdx.x + s];
      smn[threadIdx.x] = (b < a) ? b : a;
      unsigned c = smx[threadIdx.x], d = smx[threadIdx.x + s];
      smx[threadIdx.x] = (d > c) ? d : c;
    }
    __syncthreads();
  }
  if (threadIdx.x == 0) { atomicMin(&mm[0], smn[0]); atomicMax(&mm[1], smx[0]); }
}

__global__ void scan_kernel(const int* __restrict__ deg, int* offs, int* cursor) {
  __shared__ int part[1024];
  const int CH = (NN + 1023) / 1024;  // 20
  int t = threadIdx.x;
  int b = t * CH;
  int e = (b + CH < NN) ? (b + CH) : NN;
  int s = 0;
  for (int i = b; i < e; ++i) s += deg[i];
  part[t] = s;
  __syncthreads();
  for (int off = 1; off < 1024; off <<= 1) {
    int v = part[t];
    int add = (t >= off) ? part[t - off] : 0;
    __syncthreads();
    part[t] = v + add;
    __syncthreads();
  }
  int excl = (t == 0) ? 0 : part[t - 1];
  for (int i = b; i < e; ++i) { offs[i] = excl; cursor[i] = excl; excl += deg[i]; }
  if (t == 1023) offs[NN] = part[1023];
}

// fill CSR + warm-stream xb into L2/L3 (DCE-proof sink, rule #17)
__global__ void fill_kernel(const int* __restrict__ src, const int* __restrict__ dst,
                            const int* __restrict__ et, const float* __restrict__ ew,
                            const unsigned* __restrict__ mm, int* cursor,
                            int2* __restrict__ ed, const uint4* __restrict__ xb4) {
  int e = blockIdx.x * blockDim.x + threadIdx.x;
  if (e >= NE) return;
  float mn = ord2f(mm[0]), mx = ord2f(mm[1]);
  float inv = 1.0f / (mx - mn + 1e-8f);
  int d = dst[e];
  int pos = atomicAdd(&cursor[d], 1);
  ed[pos] = make_int2(src[e] | (et[e] << 28), __float_as_int((ew[e] - mn) * inv));
  // warm: NE threads x 16B = 5.12 MB = exactly NN*FD bf16
  uint4 wv = xb4[e];
  asm volatile("" :: "v"(wv.x), "v"(wv.y), "v"(wv.z), "v"(wv.w));
}

// warm-stream a buffer (h1 between gemm1 and agg2)
__global__ void warm_kernel(const uint4* __restrict__ p, int n4) {
  int i = blockIdx.x * blockDim.x + threadIdx.x;
  if (i < n4) {
    uint4 v = p[i];
    asm volatile("" :: "v"(v.x), "v"(v.y), "v"(v.z), "v"(v.w));
  }
}

// ---------------------------------------------------------------------------
// Aggregation (R3-champion body, bf16 input both layers): one wave per node,
// unroll-4 edge gather, branchless relation select. Writes unified A row
// g[node][640]: 4 relation slots + own-row copy (root).
// ---------------------------------------------------------------------------
__global__ __launch_bounds__(256) void aggregate_kernel(
    const unsigned* __restrict__ xb,   // [NN][64] packed bf16 pairs
    const int* __restrict__ offs, const int2* __restrict__ ed,
    __bf16* __restrict__ g) {
  int node = (int)((blockIdx.x * blockDim.x + threadIdx.x) >> 6);
  int lane = threadIdx.x & 63;
  if (node >= NN) return;
  int beg = offs[node], end = offs[node + 1];
  float a00 = 0.f, a01 = 0.f, a10 = 0.f, a11 = 0.f;
  float a20 = 0.f, a21 = 0.f, a30 = 0.f, a31 = 0.f;

#define LOADP(E, P0, P1)                                                \
  do {                                                                  \
    int zs_ = (E).x & 0x0FFFFFFF;                                       \
    unsigned zu_ = xb[(size_t)zs_ * 64 + lane];                         \
    P0 = __uint_as_float(zu_ << 16);                                    \
    P1 = __uint_as_float(zu_ & 0xFFFF0000u);                            \
  } while (0)
#define ACCP(E, P0, P1)                                                 \
  do {                                                                  \
    float zw_ = __int_as_float((E).y);                                  \
    unsigned zr_ = ((unsigned)(E).x) >> 28;                             \
    float zw0_ = (zr_ == 0) ? zw_ : 0.f;                                \
    float zw1_ = (zr_ == 1) ? zw_ : 0.f;                                \
    float zw2_ = (zr_ == 2) ? zw_ : 0.f;                                \
    float zw3_ = (zr_ == 3) ? zw_ : 0.f;                                \
    a00 += zw0_ * (P0); a01 += zw0_ * (P1);                             \
    a10 += zw1_ * (P0); a11 += zw1_ * (P1);                             \
    a20 += zw2_ * (P0); a21 += zw2_ * (P1);                             \
    a30 += zw3_ * (P0); a31 += zw3_ * (P1);                             \
  } while (0)

  int j = beg;
  for (; j + 4 <= end; j += 4) {
    int2 e0 = ed[j], e1 = ed[j + 1], e2 = ed[j + 2], e3 = ed[j + 3];
    float p00, p01, p10, p11, p20, p21, p30, p31;
    LOADP(e0, p00, p01); LOADP(e1, p10, p11);
    LOADP(e2, p20, p21); LOADP(e3, p30, p31);
    ACCP(e0, p00, p01); ACCP(e1, p10, p11);
    ACCP(e2, p20, p21); ACCP(e3, p30, p31);
  }
  for (; j < end; ++j) {
    int2 e = ed[j];
    float p0, p1;
    LOADP(e, p0, p1);
    ACCP(e, p0, p1);
  }
#undef LOADP
#undef ACCP

  unsigned* g32 = (unsigned*)(g + (size_t)node * KTOT);
  g32[0 * 64 + lane] = pkbf(a00, a01);
  g32[1 * 64 + lane] = pkbf(a10, a11);
  g32[2 * 64 + lane] = pkbf(a20, a21);
  g32[3 * 64 + lane] = pkbf(a30, a31);
  g32[4 * 64 + lane] = xb[(size_t)node * 64 + lane];  // root/self
}

// ---------------------------------------------------------------------------
// GEMM (R3-champion verbatim): out[m][n] = gA[m][:] @ wt[n][:] + bias[n].
// 512 thr (8 waves): wave -> (wr=w>>1 rows wr*16.., wc=w&1 cols wc*64..).
// Double-buffered LDS, global_load_lds width-16 staging, BK=32.
// ---------------------------------------------------------------------------
template <int OUT_BF16>
__global__ __launch_bounds__(512) void gemm_kernel(
    const __bf16* __restrict__ gA, const __bf16* __restrict__ wt,
    const float* __restrict__ bias, float* __restrict__ outf,
    __bf16* __restrict__ outb) {
  __shared__ __bf16 As[2][64 * 32];
  __shared__ __bf16 Bs[2][128 * 32];
  int tid = threadIdx.x;
  int wave = tid >> 6, lane = tid & 63;
  int wr = wave >> 1, wc = wave & 1;
  int m0 = blockIdx.x * 64;
  int rl = wr * 16 + (lane & 15);
  int kfe = (lane >> 4) * 8;  // k-slice elem offset within 32-elem row

  // ---- layout probe (self-decodes acc-slot -> (row,col); R3-verified) ----
  unsigned rowpack = 0, colpack[4];
  {
    int arow = tid >> 3, akof = (tid & 7) * 4;   // 64 rows x 32 k, bf16x4/thread
    int bn = tid >> 2, bkof = (tid & 3) * 8;     // 128 rows x 32 k, bf16x8/thread
    bf16x4 v4, one4;
    bf16x8 v8, one8;
#pragma unroll
    for (int i = 0; i < 4; ++i) one4[i] = (__bf16)1.0f;
#pragma unroll
    for (int i = 0; i < 8; ++i) one8[i] = (__bf16)1.0f;
    __bf16 rv = (__bf16)((float)arow * 0.015625f);  // row/64, exact
#pragma unroll
    for (int i = 0; i < 4; ++i) v4[i] = rv;
    *(bf16x4*)(&As[0][arow * 32 + akof]) = v4;
    *(bf16x8*)(&Bs[0][bn * 32 + bkof]) = one8;
    __syncthreads();
    bf16x8 pa = *(const bf16x8*)(&As[0][rl * 32 + kfe]);
    bf16x8 pb = *(const bf16x8*)(&Bs[0][(wc * 64 + (lane & 15)) * 32 + kfe]);
    f32x4 P1 = __builtin_amdgcn_mfma_f32_16x16x32_bf16(pa, pb, (f32x4){0.f, 0.f, 0.f, 0.f}, 0, 0, 0);
    __syncthreads();
    __bf16 cv = (__bf16)((float)bn * 0.0078125f);  // col/128, exact
#pragma unroll
    for (int i = 0; i < 8; ++i) v8[i] = cv;
    *(bf16x4*)(&As[0][arow * 32 + akof]) = one4;
    *(bf16x8*)(&Bs[0][bn * 32 + bkof]) = v8;
    __syncthreads();
    bf16x8 pa1 = *(const bf16x8*)(&As[0][rl * 32 + kfe]);
#pragma unroll
    for (int j = 0; j < 4; ++j)
      rowpack |= ((unsigned)(int)(P1[j] * 2.0f + 0.5f)) << (8 * j);
#pragma unroll
    for (int fn = 0; fn < 4; ++fn) {
      bf16x8 pbc = *(const bf16x8*)(&Bs[0][(wc * 64 + fn * 16 + (lane & 15)) * 32 + kfe]);
      f32x4 P2 = __builtin_amdgcn_mfma_f32_16x16x32_bf16(pa1, pbc, (f32x4){0.f, 0.f, 0.f, 0.f}, 0, 0, 0);
      unsigned cp = 0;
#pragma unroll
      for (int j = 0; j < 4; ++j)
        cp |= ((unsigned)(int)(P2[j] * 4.0f + 0.5f)) << (8 * j);
      colpack[fn] = cp;
    }
    __syncthreads();  // probe reads done before staging overwrites buf 0
  }

  f32x4 acc[4];
#pragma unroll
  for (int i = 0; i < 4; ++i) acc[i] = (f32x4){0.f, 0.f, 0.f, 0.f};

  // staging: tid<256 -> A tile (64x32), tid>=256 -> B tile (128x32, 2 chunks)
  auto stage = [&](int buf, int k0) {
    if (tid < 256) {
      int row = tid >> 2;
      int m = m0 + row;
      if (m >= NN) m = NN - 1;
      gld16(gA + (size_t)m * KTOT + k0 + (tid & 3) * 8, &As[buf][(tid >> 6) * 512]);
    } else {
      int t = tid - 256;
      int wv = t >> 6;
      int r0 = t >> 2;
      gld16(wt + (size_t)r0 * KTOT + k0 + (t & 3) * 8, &Bs[buf][wv * 512]);
      gld16(wt + (size_t)(64 + r0) * KTOT + k0 + (t & 3) * 8, &Bs[buf][2048 + wv * 512]);
    }
  };

  stage(0, 0);
  __syncthreads();  // drains vmcnt -> buf0 ready
  int cur = 0;
  for (int step = 0; step < NSTEP; ++step) {
    if (step + 1 < NSTEP) stage(cur ^ 1, (step + 1) * 32);  // prefetch next tile
    bf16x8 a = *(const bf16x8*)(&As[cur][rl * 32 + kfe]);
#pragma unroll
    for (int fn = 0; fn < 4; ++fn) {
      bf16x8 b = *(const bf16x8*)(&Bs[cur][(wc * 64 + fn * 16 + (lane & 15)) * 32 + kfe]);
      acc[fn] = __builtin_amdgcn_mfma_f32_16x16x32_bf16(a, b, acc[fn], 0, 0, 0);
    }
    __syncthreads();  // drains prefetch + everyone's reads of buf cur
    cur ^= 1;
  }

  // epilogue: probe-decoded (row,col) per slot
#pragma unroll
  for (int fn = 0; fn < 4; ++fn) {
#pragma unroll
    for (int j = 0; j < 4; ++j) {
      int rloc = (int)((rowpack >> (8 * j)) & 255u);
      int col = (int)((colpack[fn] >> (8 * j)) & 255u);
      int m = m0 + rloc;
      if (m < NN) {
        float v = acc[fn][j] + bias[col];
        if (OUT_BF16) {
          v = fmaxf(v, 0.f);
          outb[(size_t)m * FD + col] = (__bf16)v;
        } else {
          outf[(size_t)m * FD + col] = v;
        }
      }
    }
  }
}

extern "C" void kernel_launch(void* const* d_in, const int* in_sizes, int n_in,
                              void* d_out, int out_size, void* d_ws, size_t ws_size,
                              hipStream_t stream) {
  const float* x  = (const float*)d_in[0];
  const int*   ei = (const int*)d_in[1];
  const int*   et = (const int*)d_in[2];
  const float* ew = (const float*)d_in[3];
  const float* W1 = (const float*)d_in[4];
  const float* r1 = (const float*)d_in[5];
  const float* b1 = (const float*)d_in[6];
  const float* W2 = (const float*)d_in[7];
  const float* r2 = (const float*)d_in[8];
  const float* b2 = (const float*)d_in[9];
  float* out = (float*)d_out;
  const int* src = ei;
  const int* dst = ei + NE;

  char* w = (char*)d_ws;
  size_t o = 0;
  auto take = [&](size_t bytes) -> char* {
    char* p = w + o;
    o += (bytes + 255) & ~(size_t)255;
    return p;
  };
  unsigned* mm  = (unsigned*)take(8);
  int* deg      = (int*)take((size_t)NN * 4);
  int* offs     = (int*)take((size_t)(NN + 1) * 4);
  int* cursor   = (int*)take((size_t)NN * 4);
  int2* ed      = (int2*)take((size_t)(NE + 8) * 8);
  unsigned* xb  = (unsigned*)take((size_t)NN * 64 * 4);
  __bf16* g     = (__bf16*)take((size_t)NN * KTOT * 2);
  __bf16* h1    = (__bf16*)take((size_t)NN * FD * 2);
  __bf16* wt1   = (__bf16*)take((size_t)FD * KTOT * 2);
  __bf16* wt2   = (__bf16*)take((size_t)FD * KTOT * 2);
  (void)ws_size; (void)n_in; (void)in_sizes; (void)out_size;

  hipLaunchKernelGGL(prep_kernel, dim3((NN * FD / 4 + 255) / 256), dim3(256), 0, stream,
                     mm, deg, x, xb, W1, r1, W2, r2, wt1, wt2);
  hipLaunchKernelGGL(histmm_kernel, dim3(512), dim3(256), 0, stream, dst, ew, deg, mm);
  hipLaunchKernelGGL(scan_kernel, dim3(1), dim3(1024), 0, stream, deg, offs, cursor);
  hipLaunchKernelGGL(fill_kernel, dim3((NE + 255) / 256), dim3(256), 0, stream,
                     src, dst, et, ew, mm, cursor, ed, (const uint4*)xb);
  // layer 1
  hipLaunchKernelGGL(aggregate_kernel, dim3(NN / 4), dim3(256), 0, stream, xb, offs, ed, g);
  hipLaunchKernelGGL((gemm_kernel<1>), dim3((NN + 63) / 64), dim3(512), 0, stream,
                     g, wt1, b1, (float*)nullptr, h1);
  // warm h1 for layer-2 gathers (written spread across XCD L2s; stream to L3)
  hipLaunchKernelGGL(warm_kernel, dim3((NN * 64 / 4 + 255) / 256), dim3(256), 0, stream,
                     (const uint4*)h1, NN * 64 / 4);
  // layer 2
  hipLaunchKernelGGL(aggregate_kernel, dim3(NN / 4), dim3(256), 0, stream,
                     (const unsigned*)h1, offs, ed, g);
  hipLaunchKernelGGL((gemm_kernel<0>), dim3((NN + 63) / 64), dim3(512), 0, stream,
                     g, wt2, b2, out, (__bf16*)nullptr);
}